// Round 2
// baseline (572.455 us; speedup 1.0000x reference)
//
#include <hip/hip_runtime.h>
#include <hip/hip_bf16.h>

#define AS1 __attribute__((address_space(1)))
#define AS3 __attribute__((address_space(3)))

typedef __bf16 bf16_t;
typedef __attribute__((ext_vector_type(8))) __bf16 bf16x8;
typedef __attribute__((ext_vector_type(4))) float f32x4;

static constexpr int BSZ = 4, SEQ = 2048, HID = 512, PROJ = 4096;
static constexpr long NROW = (long)BSZ * SEQ;  // 8192
static constexpr float SCALE = 0.125f;

__device__ __forceinline__ void gload_lds16(const void* g, void* l) {
  __builtin_amdgcn_global_load_lds((const AS1 void*)g, (AS3 void*)l, 16, 0, 0);
}

__device__ __forceinline__ float bf2f(unsigned short u) {
  union { unsigned u32; float f; } x; x.u32 = ((unsigned)u) << 16; return x.f;
}

// ------------------------------------------------------------------
// GEMM: C[M,N] = epi(A[M,K] . B[N,K]^T), A/B row-major bf16 with row
// strides lda/ldb. z batching via element strides sA/sB/sC.
// epi: EXP ? exp(acc + ra[z*sRab+row] + rb[z*sRab+col])
//          : (acc + bias[col]) * scale
// 128x128 tile, BK=64, 256 threads (4 waves, 2x2, 64x64/wave).
// LDS XOR swizzle (byte ^= (row&7)<<4): linear LDS dest, inverse-swizzled
// global source, swizzled ds_read (rule 21).
// ------------------------------------------------------------------
template <typename OutT, bool EXP>
__global__ __launch_bounds__(256) void gemm_bt(
    const bf16_t* __restrict__ A, const bf16_t* __restrict__ B,
    OutT* __restrict__ C, const float* __restrict__ bias,
    const float* __restrict__ ra, const float* __restrict__ rb,
    float scale, int M, int N, int K, long lda, long ldb,
    long sA, long sB, long sC, long sRab)
{
  __shared__ __align__(16) bf16_t As[128 * 64];
  __shared__ __align__(16) bf16_t Bs[128 * 64];
  const int z = blockIdx.z;
  A += (long)z * sA; B += (long)z * sB; C += (long)z * sC;
  const int tid  = threadIdx.x;
  const int lane = tid & 63;
  const int wid  = tid >> 6;
  const int wr = (wid >> 1) * 64;
  const int wc = (wid & 1) * 64;
  const long rowBase = (long)blockIdx.y * 128;
  const long colBase = (long)blockIdx.x * 128;

  f32x4 acc[4][4] = {};

  int srow[4], scol[4];
#pragma unroll
  for (int i = 0; i < 4; ++i) {
    int li = i * 256 + tid;
    int row = li >> 3;
    int inner = (li & 7) << 4;
    int src = inner ^ ((row & 7) << 4);
    srow[i] = row;
    scol[i] = src >> 1;
  }

  for (int k0 = 0; k0 < K; k0 += 64) {
    __syncthreads();
#pragma unroll
    for (int i = 0; i < 4; ++i) {
      int li = i * 256 + tid;
      gload_lds16(A + (rowBase + srow[i]) * lda + k0 + scol[i], (char*)As + li * 16);
      gload_lds16(B + (colBase + srow[i]) * ldb + k0 + scol[i], (char*)Bs + li * 16);
    }
    __syncthreads();
#pragma unroll
    for (int kk = 0; kk < 64; kk += 32) {
      const int kb = (kk + ((lane >> 4) << 3)) << 1;
      bf16x8 af[4], bfr[4];
#pragma unroll
      for (int m = 0; m < 4; ++m) {
        int row = wr + m * 16 + (lane & 15);
        int off = (row << 7) + (kb ^ ((row & 7) << 4));
        af[m] = *(const bf16x8*)((const char*)As + off);
      }
#pragma unroll
      for (int n = 0; n < 4; ++n) {
        int row = wc + n * 16 + (lane & 15);
        int off = (row << 7) + (kb ^ ((row & 7) << 4));
        bfr[n] = *(const bf16x8*)((const char*)Bs + off);
      }
#pragma unroll
      for (int m = 0; m < 4; ++m)
#pragma unroll
        for (int n = 0; n < 4; ++n)
          acc[m][n] = __builtin_amdgcn_mfma_f32_16x16x32_bf16(af[m], bfr[n], acc[m][n], 0, 0, 0);
    }
  }

#pragma unroll
  for (int n = 0; n < 4; ++n) {
    const long col = colBase + wc + n * 16 + (lane & 15);
    const float bv_ = (!EXP && bias) ? bias[col] : 0.0f;
    const float rbv = (EXP && rb) ? rb[z * sRab + col] : 0.0f;
#pragma unroll
    for (int m = 0; m < 4; ++m) {
#pragma unroll
      for (int e = 0; e < 4; ++e) {
        const long row = rowBase + wr + m * 16 + (lane >> 4) * 4 + e;
        float v0 = acc[m][n][e];
        float v;
        if (EXP) {
          float rav = ra ? ra[z * sRab + row] : 0.0f;
          v = __expf(v0 + rav + rbv);
        } else {
          v = (v0 + bv_) * scale;
        }
        C[row * N + col] = (OutT)v;
      }
    }
  }
}

// f32 [R,C] -> bf16 [R,3C] hi/lo split, thirds selected by s0/s1/s2 (0=hi,1=lo)
__global__ void split3(const float* __restrict__ in, bf16_t* __restrict__ out,
                       long n, int cshift, int s0, int s1, int s2) {
  long C = 1L << cshift;
  for (long i = (long)blockIdx.x * blockDim.x + threadIdx.x; i < n;
       i += (long)gridDim.x * blockDim.x) {
    long r = i >> cshift, c = i & (C - 1);
    float x = in[i];
    bf16_t h = (bf16_t)x;
    bf16_t l = (bf16_t)(x - (float)h);
    bf16_t* o = out + r * 3 * C + c;
    o[0]     = s0 ? l : h;
    o[C]     = s1 ? l : h;
    o[2 * C] = s2 ? l : h;
  }
}

// fp32 -> bf16 elementwise
__global__ void cast_f32_bf16(const float* __restrict__ in, bf16_t* __restrict__ out, long n) {
  long i0 = ((long)blockIdx.x * blockDim.x + threadIdx.x) * 4;
  long stride = (long)gridDim.x * blockDim.x * 4;
  for (long i = i0; i < n; i += stride) {
    float4 f = *(const float4*)(in + i);
    union { ushort4 u; bf16_t h[4]; } o;
    o.h[0] = (bf16_t)f.x; o.h[1] = (bf16_t)f.y; o.h[2] = (bf16_t)f.z; o.h[3] = (bf16_t)f.w;
    *(ushort4*)(out + i) = o.u;
  }
}

// fp32 [R,C] -> bf16 [C,R]
__global__ void transpose_cast(const float* __restrict__ in, bf16_t* __restrict__ out, int R, int C) {
  __shared__ float tile[32][33];
  int c0 = blockIdx.x * 32, r0 = blockIdx.y * 32;
  int tx = threadIdx.x & 31, ty = threadIdx.x >> 5;
#pragma unroll
  for (int i = 0; i < 32; i += 8)
    tile[ty + i][tx] = in[(long)(r0 + ty + i) * C + (c0 + tx)];
  __syncthreads();
#pragma unroll
  for (int i = 0; i < 32; i += 8)
    out[(long)(c0 + ty + i) * R + (r0 + tx)] = (bf16_t)tile[tx][ty + i];
}

// reduce K-split partials: G = scale * sum_p parts[p]
__global__ void reduceG(const float* __restrict__ parts, float* __restrict__ G,
                        float scale, int nElem, int nParts) {
  int i = blockIdx.x * 256 + threadIdx.x;
  if (i < nElem) {
    float s = 0.f;
    for (int p = 0; p < nParts; ++p) s += parts[(long)p * nElem + i];
    G[i] = scale * s;
  }
}

// y[r] = sum_c M[r,c]*b[c]
__global__ void matvec(const float* __restrict__ M, const float* __restrict__ b,
                       float* __restrict__ y, int C) {
  __shared__ float red[256];
  int r = blockIdx.x;
  float s = 0.f;
  for (int j = threadIdx.x; j < C; j += 256) s += M[(long)r * C + j] * b[j];
  red[threadIdx.x] = s; __syncthreads();
  for (int w = 128; w > 0; w >>= 1) {
    if (threadIdx.x < w) red[threadIdx.x] += red[threadIdx.x + w];
    __syncthreads();
  }
  if (threadIdx.x == 0) y[r] = red[0];
}

// out[r] = scale*(sum_h X[r,h]*y[h] + *cptr)
__global__ void rowdot(const float* __restrict__ X, const float* __restrict__ y,
                       const float* __restrict__ cptr, float scale,
                       float* __restrict__ out, int C) {
  __shared__ float red[256];
  int r = blockIdx.x;
  float s = 0.f;
  for (int j = threadIdx.x; j < C; j += 256) s += X[(long)r * C + j] * y[j];
  red[threadIdx.x] = s; __syncthreads();
  for (int w = 128; w > 0; w >>= 1) {
    if (threadIdx.x < w) red[threadIdx.x] += red[threadIdx.x + w];
    __syncthreads();
  }
  if (threadIdx.x == 0) out[r] = scale * (red[0] + (cptr ? *cptr : 0.f));
}

// *out = sum a[i]*b[i]
__global__ void dotk(const float* __restrict__ a, const float* __restrict__ b,
                     float* __restrict__ out, int n) {
  __shared__ float red[256];
  float s = 0.f;
  for (int j = threadIdx.x; j < n; j += 256) s += a[j] * b[j];
  red[threadIdx.x] = s; __syncthreads();
  for (int w = 128; w > 0; w >>= 1) {
    if (threadIdx.x < w) red[threadIdx.x] += red[threadIdx.x + w];
    __syncthreads();
  }
  if (threadIdx.x == 0) *out = red[0];
}

// partial column sums of P: part[(chunk*Z)+z][m]
__global__ void colsum_part(const bf16_t* __restrict__ P, float* __restrict__ part,
                            int Nn, int Nm, int rowsPer) {
  int z = blockIdx.z;
  int m = blockIdx.x * 256 + threadIdx.x;
  int n0 = blockIdx.y * rowsPer;
  const bf16_t* Pp = P + (long)z * Nn * Nm;
  float s = 0.f;
  for (int n = n0; n < n0 + rowsPer; ++n)
    s += (float)Pp[(long)n * Nm + m];
  part[((long)blockIdx.y * gridDim.z + z) * Nm + m] = s;
}

__global__ void colsum_final(const float* __restrict__ part, float* __restrict__ crcp,
                             int Nm, int nParts) {
  int b = blockIdx.y;
  int m = blockIdx.x * 256 + threadIdx.x;
  float s = 0.f;
  for (int p = 0; p < nParts; ++p)
    s += part[((long)p * gridDim.y + b) * Nm + m];
  crcp[(long)b * Nm + m] = 1.0f / s;
}

// bf16 [R,C] -> bf16 [C,R], scaling input row r by crcp[z*R+r]
__global__ void transpose_scale_bf16(const bf16_t* __restrict__ in, const float* __restrict__ crcp,
                                     bf16_t* __restrict__ out, int R, int C, long sIn, long sOut) {
  __shared__ bf16_t tile[64][68];
  int z = blockIdx.z;
  const bf16_t* ip = in + (long)z * sIn;
  bf16_t* op = out + (long)z * sOut;
  const float* rc = crcp + (long)z * R;
  int c0 = blockIdx.x * 64, r0 = blockIdx.y * 64;
#pragma unroll
  for (int i = 0; i < 4; ++i) {
    int chunk = i * 256 + threadIdx.x;
    int r = chunk >> 4, c4 = (chunk & 15) << 2;
    float s = rc[r0 + r];
    ushort4 uv = *(const ushort4*)(ip + (long)(r0 + r) * C + (c0 + c4));
    tile[r][c4 + 0] = (bf16_t)(bf2f(uv.x) * s);
    tile[r][c4 + 1] = (bf16_t)(bf2f(uv.y) * s);
    tile[r][c4 + 2] = (bf16_t)(bf2f(uv.z) * s);
    tile[r][c4 + 3] = (bf16_t)(bf2f(uv.w) * s);
  }
  __syncthreads();
#pragma unroll
  for (int i = 0; i < 4; ++i) {
    int chunk = i * 256 + threadIdx.x;
    int oc = chunk >> 4, or4 = (chunk & 15) << 2;
    union { ushort4 u; bf16_t h[4]; } o;
    o.h[0] = tile[or4 + 0][oc];
    o.h[1] = tile[or4 + 1][oc];
    o.h[2] = tile[or4 + 2][oc];
    o.h[3] = tile[or4 + 3][oc];
    *(ushort4*)(op + (long)(c0 + oc) * R + (r0 + or4)) = o.u;
  }
}

extern "C" void kernel_launch(void* const* d_in, const int* in_sizes, int n_in,
                              void* d_out, int out_size, void* d_ws, size_t ws_size,
                              hipStream_t stream)
{
  (void)in_sizes; (void)n_in; (void)out_size; (void)ws_size;
  const float* q  = (const float*)d_in[0];
  const float* k  = (const float*)d_in[1];
  const float* v  = (const float*)d_in[2];
  const float* Wq = (const float*)d_in[3];
  const float* bq = (const float*)d_in[4];
  const float* Wk = (const float*)d_in[5];
  const float* bk = (const float*)d_in[6];
  const float* Wv = (const float*)d_in[7];
  const float* bv = (const float*)d_in[8];
  const float* Wo = (const float*)d_in[9];
  const float* bo = (const float*)d_in[10];
  float* out = (float*)d_out;

  char* ws = (char*)d_ws;
  const size_t MB = 1u << 20;
  // ws overlay, peak 180 MB:
  bf16_t* qcat  = (bf16_t*)(ws);             // [0,24)   [8192,1536] (qh|ql|qh)
  bf16_t* kcat  = (bf16_t*)(ws + 24 * MB);   // [24,48)  [8192,1536] (kh|kh|kl)
  bf16_t* GA    = (bf16_t*)(ws + 48 * MB);   // [48,60)  [512,12288] from Wk (h|l|h)
  bf16_t* GB    = (bf16_t*)(ws + 60 * MB);   // [60,72)  [512,12288] from Wq (h|h|l)
  float*  Gpart = (float*)(ws + 72 * MB);    // [72,88)  16x[512,512]
  float*  Gt    = (float*)(ws + 88 * MB);    // [88,89)  [512,512] = SCALE*Wk.Wq^T
  bf16_t* Gtcat = (bf16_t*)(ws + 89 * MB);   // [89,91)  [512,1536] (h|h|l)
  float*  tbuf  = (float*)(ws + 91 * MB);    // [91,107) [8192,512] t = q.G
  bf16_t* tcat  = (bf16_t*)(ws + 107 * MB);  // [107,131) [8192,1536] (th|tl|th)
  float*  wqbk  = (float*)(ws + 131 * MB);            // 2 KB
  float*  wkbq  = (float*)(ws + 131 * MB + 16 * 1024);
  float*  cdot  = (float*)(ws + 131 * MB + 32 * 1024);
  float*  rav   = (float*)(ws + 131 * MB + 64 * 1024);   // 32 KB [8192]
  float*  rbv   = (float*)(ws + 131 * MB + 128 * 1024);  // 32 KB
  float*  crcp  = (float*)(ws + 131 * MB + 192 * 1024);  // 32 KB
  float*  part  = (float*)(ws + 131 * MB + 256 * 1024);  // 512 KB
  bf16_t* P     = (bf16_t*)(ws + 132 * MB);  // [132,164) 4x[2048,2048] exp(scores)
  bf16_t* vbf   = (bf16_t*)(ws + 164 * MB);  // [164,172)
  bf16_t* WvT   = (bf16_t*)(ws + 172 * MB);  // [172,176) [4096,512]
  bf16_t* WoT   = (bf16_t*)(ws + 176 * MB);  // [176,180) [512,4096]
  bf16_t* vp    = (bf16_t*)(ws);             // [0,64) reuse (qcat/kcat dead)
  bf16_t* vpT   = (bf16_t*)(ws + 64 * MB);   // [64,128) reuse (G/t stuff dead)
  bf16_t* xb    = (bf16_t*)(ws);             // [0,64) reuse (vp dead)

  // 1) hi/lo splits: A-operands (h,l,h), B-operands (h,h,l)
  split3<<<2048, 256, 0, stream>>>(q,  qcat, NROW * HID, 9, 0, 1, 0);
  split3<<<2048, 256, 0, stream>>>(k,  kcat, NROW * HID, 9, 0, 0, 1);
  split3<<<2048, 256, 0, stream>>>(Wk, GA, (long)HID * PROJ, 12, 0, 1, 0);
  split3<<<2048, 256, 0, stream>>>(Wq, GB, (long)HID * PROJ, 12, 0, 0, 1);

  // 2) Gt = Wk . Wq^T (K=12288 split into 16 z-chunks of 768), then *SCALE, split
  gemm_bt<float, false><<<dim3(4, 4, 16), 256, 0, stream>>>(GA, GB, Gpart,
      nullptr, nullptr, nullptr, 1.0f, HID, HID, 768, 3L * PROJ, 3L * PROJ,
      768, 768, (long)HID * HID, 0);
  reduceG<<<(HID * HID + 255) / 256, 256, 0, stream>>>(Gpart, Gt, SCALE, HID * HID, 16);
  split3<<<1024, 256, 0, stream>>>(Gt, Gtcat, (long)HID * HID, 9, 0, 0, 1);

  // 3) t = q . Gt^T  (split x split, K=1536), f32 out, then split
  gemm_bt<float, false><<<dim3(4, 64, 1), 256, 0, stream>>>(qcat, Gtcat, tbuf,
      nullptr, nullptr, nullptr, 1.0f, (int)NROW, HID, 1536, 1536, 1536, 0, 0, 0, 0);
  split3<<<2048, 256, 0, stream>>>(tbuf, tcat, NROW * HID, 9, 0, 1, 0);

  // 4) rank-1 bias terms: ra[n]=SCALE*(q[n].(Wq bk)+bq.bk), rb[m]=SCALE*(k[m].(Wk bq))
  matvec<<<HID, 256, 0, stream>>>(Wq, bk, wqbk, PROJ);
  matvec<<<HID, 256, 0, stream>>>(Wk, bq, wkbq, PROJ);
  dotk<<<1, 256, 0, stream>>>(bq, bk, cdot, PROJ);
  rowdot<<<(int)NROW, 256, 0, stream>>>(q, wqbk, cdot, SCALE, rav, HID);
  rowdot<<<(int)NROW, 256, 0, stream>>>(k, wkbq, nullptr, SCALE, rbv, HID);

  // 5) P = exp(t.k^T + ra + rb) per batch (scores max ~44 << 88, no max-sub)
  gemm_bt<bf16_t, true><<<dim3(16, 16, BSZ), 256, 0, stream>>>(tcat, kcat, P,
      nullptr, rav, rbv, 1.0f, SEQ, SEQ, 1536, 1536, 1536,
      (long)SEQ * 1536, (long)SEQ * 1536, (long)SEQ * SEQ, SEQ);

  // 6) column sums of P -> 1/csum
  colsum_part<<<dim3(SEQ / 256, 16, BSZ), 256, 0, stream>>>(P, part, SEQ, SEQ, SEQ / 16);
  colsum_final<<<dim3(SEQ / 256, BSZ), 256, 0, stream>>>(part, crcp, SEQ, 16);

  // 7) v path (plain bf16)
  cast_f32_bf16<<<2048, 256, 0, stream>>>(v, vbf, NROW * HID);
  transpose_cast<<<dim3(PROJ / 32, HID / 32), 256, 0, stream>>>(Wv, WvT, HID, PROJ);
  transpose_cast<<<dim3(HID / 32, PROJ / 32), 256, 0, stream>>>(Wo, WoT, PROJ, HID);
  gemm_bt<bf16_t, false><<<dim3(PROJ / 128, NROW / 128, 1), 256, 0, stream>>>(
      vbf, WvT, vp, bv, nullptr, nullptr, 1.0f, (int)NROW, PROJ, HID,
      HID, HID, 0, 0, 0, 0);

  // 8) vpT[d][m] = vp[m][d] / csum[m]
  transpose_scale_bf16<<<dim3(PROJ / 64, SEQ / 64, BSZ), 256, 0, stream>>>(
      vp, crcp, vpT, SEQ, PROJ, (long)SEQ * PROJ, (long)SEQ * PROJ);

  // 9) x = P . vpT^T  (K=2048)
  gemm_bt<bf16_t, false><<<dim3(PROJ / 128, SEQ / 128, BSZ), 256, 0, stream>>>(
      P, vpT, xb, nullptr, nullptr, nullptr, 1.0f, SEQ, PROJ, SEQ,
      SEQ, SEQ, (long)SEQ * SEQ, (long)SEQ * PROJ, (long)SEQ * PROJ, 0);

  // 10) out = x . WoT^T + bo  (f32 out)
  gemm_bt<float, false><<<dim3(HID / 128, NROW / 128, 1), 256, 0, stream>>>(
      xb, WoT, out, bo, nullptr, nullptr, 1.0f, (int)NROW, HID, PROJ,
      PROJ, PROJ, 0, 0, 0, 0);
}

// Round 3
// 383.126 us; speedup vs baseline: 1.4942x; 1.4942x over previous
//
#include <hip/hip_runtime.h>
#include <hip/hip_bf16.h>

#define AS1 __attribute__((address_space(1)))
#define AS3 __attribute__((address_space(3)))

typedef __bf16 bf16_t;
typedef __attribute__((ext_vector_type(8))) __bf16 bf16x8;
typedef __attribute__((ext_vector_type(4))) float f32x4;

static constexpr int BSZ = 4, SEQ = 2048, HID = 512, PROJ = 4096;
static constexpr long NROW = (long)BSZ * SEQ;  // 8192
static constexpr float SCALE = 0.125f;

__device__ __forceinline__ void gload_lds16(const void* g, void* l) {
  __builtin_amdgcn_global_load_lds((const AS1 void*)g, (AS3 void*)l, 16, 0, 0);
}

__device__ __forceinline__ float bf2f(unsigned short u) {
  union { unsigned u32; float f; } x; x.u32 = ((unsigned)u) << 16; return x.f;
}

// ------------------------------------------------------------------
// GEMM: C[M,N] = epi(A[M,K] . B[N,K]^T), A/B row-major bf16, row strides
// lda/ldb, z batching via element strides sA/sB/sC.
// epi: EXP ? exp(acc + ra[z*sRab+row] + rb[z*sRab+col]) : (acc+bias[col])*scale
// 128x128 tile, BK=64, 4 waves. LDS XOR swizzle (rule 21 discipline).
// ------------------------------------------------------------------
template <typename OutT, bool EXP>
__global__ __launch_bounds__(256) void gemm_bt(
    const bf16_t* __restrict__ A, const bf16_t* __restrict__ B,
    OutT* __restrict__ C, const float* __restrict__ bias,
    const float* __restrict__ ra, const float* __restrict__ rb,
    float scale, int M, int N, int K, long lda, long ldb,
    long sA, long sB, long sC, long sRab)
{
  __shared__ __align__(16) bf16_t As[128 * 64];
  __shared__ __align__(16) bf16_t Bs[128 * 64];
  const int z = blockIdx.z;
  A += (long)z * sA; B += (long)z * sB; C += (long)z * sC;
  const int tid  = threadIdx.x;
  const int lane = tid & 63;
  const int wid  = tid >> 6;
  const int wr = (wid >> 1) * 64;
  const int wc = (wid & 1) * 64;
  const long rowBase = (long)blockIdx.y * 128;
  const long colBase = (long)blockIdx.x * 128;

  f32x4 acc[4][4] = {};

  int srow[4], scol[4];
#pragma unroll
  for (int i = 0; i < 4; ++i) {
    int li = i * 256 + tid;
    int row = li >> 3;
    int inner = (li & 7) << 4;
    int src = inner ^ ((row & 7) << 4);
    srow[i] = row;
    scol[i] = src >> 1;
  }

  for (int k0 = 0; k0 < K; k0 += 64) {
    __syncthreads();
#pragma unroll
    for (int i = 0; i < 4; ++i) {
      int li = i * 256 + tid;
      gload_lds16(A + (rowBase + srow[i]) * lda + k0 + scol[i], (char*)As + li * 16);
      gload_lds16(B + (colBase + srow[i]) * ldb + k0 + scol[i], (char*)Bs + li * 16);
    }
    __syncthreads();
#pragma unroll
    for (int kk = 0; kk < 64; kk += 32) {
      const int kb = (kk + ((lane >> 4) << 3)) << 1;
      bf16x8 af[4], bfr[4];
#pragma unroll
      for (int m = 0; m < 4; ++m) {
        int row = wr + m * 16 + (lane & 15);
        int off = (row << 7) + (kb ^ ((row & 7) << 4));
        af[m] = *(const bf16x8*)((const char*)As + off);
      }
#pragma unroll
      for (int n = 0; n < 4; ++n) {
        int row = wc + n * 16 + (lane & 15);
        int off = (row << 7) + (kb ^ ((row & 7) << 4));
        bfr[n] = *(const bf16x8*)((const char*)Bs + off);
      }
#pragma unroll
      for (int m = 0; m < 4; ++m)
#pragma unroll
        for (int n = 0; n < 4; ++n)
          acc[m][n] = __builtin_amdgcn_mfma_f32_16x16x32_bf16(af[m], bfr[n], acc[m][n], 0, 0, 0);
    }
  }

#pragma unroll
  for (int n = 0; n < 4; ++n) {
    const long col = colBase + wc + n * 16 + (lane & 15);
    const float bv_ = (!EXP && bias) ? bias[col] : 0.0f;
    const float rbv = (EXP && rb) ? rb[z * sRab + col] : 0.0f;
#pragma unroll
    for (int m = 0; m < 4; ++m) {
#pragma unroll
      for (int e = 0; e < 4; ++e) {
        const long row = rowBase + wr + m * 16 + (lane >> 4) * 4 + e;
        float v0 = acc[m][n][e];
        float v;
        if (EXP) {
          float rav = ra ? ra[z * sRab + row] : 0.0f;
          v = __expf(v0 + rav + rbv);
        } else {
          v = (v0 + bv_) * scale;
        }
        C[row * N + col] = (OutT)v;
      }
    }
  }
}

// f32 [R,C] -> bf16 [R,3C] hi/lo split, thirds selected by s0/s1/s2 (0=hi,1=lo)
__global__ void split3(const float* __restrict__ in, bf16_t* __restrict__ out,
                       long n, int cshift, int s0, int s1, int s2) {
  long C = 1L << cshift;
  for (long i = (long)blockIdx.x * blockDim.x + threadIdx.x; i < n;
       i += (long)gridDim.x * blockDim.x) {
    long r = i >> cshift, c = i & (C - 1);
    float x = in[i];
    bf16_t h = (bf16_t)x;
    bf16_t l = (bf16_t)(x - (float)h);
    bf16_t* o = out + r * 3 * C + c;
    o[0]     = s0 ? l : h;
    o[C]     = s1 ? l : h;
    o[2 * C] = s2 ? l : h;
  }
}

// fp32 -> bf16 elementwise
__global__ void cast_f32_bf16(const float* __restrict__ in, bf16_t* __restrict__ out, long n) {
  long i0 = ((long)blockIdx.x * blockDim.x + threadIdx.x) * 4;
  long stride = (long)gridDim.x * blockDim.x * 4;
  for (long i = i0; i < n; i += stride) {
    float4 f = *(const float4*)(in + i);
    union { ushort4 u; bf16_t h[4]; } o;
    o.h[0] = (bf16_t)f.x; o.h[1] = (bf16_t)f.y; o.h[2] = (bf16_t)f.z; o.h[3] = (bf16_t)f.w;
    *(ushort4*)(out + i) = o.u;
  }
}

// f32 [R,C] -> f32 [C,R]
__global__ void transpose_f32(const float* __restrict__ in, float* __restrict__ out, int R, int C) {
  __shared__ float tile[32][33];
  int c0 = blockIdx.x * 32, r0 = blockIdx.y * 32;
  int tx = threadIdx.x & 31, ty = threadIdx.x >> 5;
#pragma unroll
  for (int i = 0; i < 32; i += 8)
    tile[ty + i][tx] = in[(long)(r0 + ty + i) * C + (c0 + tx)];
  __syncthreads();
#pragma unroll
  for (int i = 0; i < 32; i += 8)
    out[(long)(c0 + ty + i) * R + (r0 + tx)] = tile[tx][ty + i];
}

// reduce K-split partials: G = scale * sum_p parts[p]
__global__ void reduceG(const float* __restrict__ parts, float* __restrict__ G,
                        float scale, int nElem, int nParts) {
  int i = blockIdx.x * 256 + threadIdx.x;
  if (i < nElem) {
    float s = 0.f;
    for (int p = 0; p < nParts; ++p) s += parts[(long)p * nElem + i];
    G[i] = scale * s;
  }
}

// y[r] = sum_c M[r,c]*b[c]
__global__ void matvec(const float* __restrict__ M, const float* __restrict__ b,
                       float* __restrict__ y, int C) {
  __shared__ float red[256];
  int r = blockIdx.x;
  float s = 0.f;
  for (int j = threadIdx.x; j < C; j += 256) s += M[(long)r * C + j] * b[j];
  red[threadIdx.x] = s; __syncthreads();
  for (int w = 128; w > 0; w >>= 1) {
    if (threadIdx.x < w) red[threadIdx.x] += red[threadIdx.x + w];
    __syncthreads();
  }
  if (threadIdx.x == 0) y[r] = red[0];
}

// out[r] = scale*(sum_h X[r,h]*y[h] + *cptr)
__global__ void rowdot(const float* __restrict__ X, const float* __restrict__ y,
                       const float* __restrict__ cptr, float scale,
                       float* __restrict__ out, int C) {
  __shared__ float red[256];
  int r = blockIdx.x;
  float s = 0.f;
  for (int j = threadIdx.x; j < C; j += 256) s += X[(long)r * C + j] * y[j];
  red[threadIdx.x] = s; __syncthreads();
  for (int w = 128; w > 0; w >>= 1) {
    if (threadIdx.x < w) red[threadIdx.x] += red[threadIdx.x + w];
    __syncthreads();
  }
  if (threadIdx.x == 0) out[r] = scale * (red[0] + (cptr ? *cptr : 0.f));
}

// *out = sum a[i]*b[i]
__global__ void dotk(const float* __restrict__ a, const float* __restrict__ b,
                     float* __restrict__ out, int n) {
  __shared__ float red[256];
  float s = 0.f;
  for (int j = threadIdx.x; j < n; j += 256) s += a[j] * b[j];
  red[threadIdx.x] = s; __syncthreads();
  for (int w = 128; w > 0; w >>= 1) {
    if (threadIdx.x < w) red[threadIdx.x] += red[threadIdx.x + w];
    __syncthreads();
  }
  if (threadIdx.x == 0) *out = red[0];
}

// partial column sums of P: part[(chunk*Z)+z][m]
__global__ void colsum_part(const bf16_t* __restrict__ P, float* __restrict__ part,
                            int Nn, int Nm, int rowsPer) {
  int z = blockIdx.z;
  int m = blockIdx.x * 256 + threadIdx.x;
  int n0 = blockIdx.y * rowsPer;
  const bf16_t* Pp = P + (long)z * Nn * Nm;
  float s = 0.f;
  for (int n = n0; n < n0 + rowsPer; ++n)
    s += (float)Pp[(long)n * Nm + m];
  part[((long)blockIdx.y * gridDim.z + z) * Nm + m] = s;
}

__global__ void colsum_final(const float* __restrict__ part, float* __restrict__ crcp,
                             int Nm, int nParts) {
  int b = blockIdx.y;
  int m = blockIdx.x * 256 + threadIdx.x;
  float s = 0.f;
  for (int p = 0; p < nParts; ++p)
    s += part[((long)p * gridDim.y + b) * Nm + m];
  crcp[(long)b * Nm + m] = 1.0f / s;
}

// bf16 [R,C] -> bf16 [C,R], scaling input row r by crcp[z*R+r]
__global__ void transpose_scale_bf16(const bf16_t* __restrict__ in, const float* __restrict__ crcp,
                                     bf16_t* __restrict__ out, int R, int C, long sIn, long sOut) {
  __shared__ bf16_t tile[64][68];
  int z = blockIdx.z;
  const bf16_t* ip = in + (long)z * sIn;
  bf16_t* op = out + (long)z * sOut;
  const float* rc = crcp + (long)z * R;
  int c0 = blockIdx.x * 64, r0 = blockIdx.y * 64;
#pragma unroll
  for (int i = 0; i < 4; ++i) {
    int chunk = i * 256 + threadIdx.x;
    int r = chunk >> 4, c4 = (chunk & 15) << 2;
    float s = rc[r0 + r];
    ushort4 uv = *(const ushort4*)(ip + (long)(r0 + r) * C + (c0 + c4));
    tile[r][c4 + 0] = (bf16_t)(bf2f(uv.x) * s);
    tile[r][c4 + 1] = (bf16_t)(bf2f(uv.y) * s);
    tile[r][c4 + 2] = (bf16_t)(bf2f(uv.z) * s);
    tile[r][c4 + 3] = (bf16_t)(bf2f(uv.w) * s);
  }
  __syncthreads();
#pragma unroll
  for (int i = 0; i < 4; ++i) {
    int chunk = i * 256 + threadIdx.x;
    int oc = chunk >> 4, or4 = (chunk & 15) << 2;
    union { ushort4 u; bf16_t h[4]; } o;
    o.h[0] = tile[or4 + 0][oc];
    o.h[1] = tile[or4 + 1][oc];
    o.h[2] = tile[or4 + 2][oc];
    o.h[3] = tile[or4 + 3][oc];
    *(ushort4*)(op + (long)(c0 + oc) * R + (r0 + or4)) = o.u;
  }
}

extern "C" void kernel_launch(void* const* d_in, const int* in_sizes, int n_in,
                              void* d_out, int out_size, void* d_ws, size_t ws_size,
                              hipStream_t stream)
{
  (void)in_sizes; (void)n_in; (void)out_size; (void)ws_size;
  const float* q  = (const float*)d_in[0];
  const float* k  = (const float*)d_in[1];
  const float* v  = (const float*)d_in[2];
  const float* Wq = (const float*)d_in[3];
  const float* bq = (const float*)d_in[4];
  const float* Wk = (const float*)d_in[5];
  const float* bk = (const float*)d_in[6];
  const float* Wv = (const float*)d_in[7];
  const float* bv = (const float*)d_in[8];
  const float* Wo = (const float*)d_in[9];
  const float* bo = (const float*)d_in[10];
  float* out = (float*)d_out;

  char* ws = (char*)d_ws;
  const size_t MB = 1u << 20;
  // ---- phase A (score path), peak 164 MB ----
  bf16_t* qcat  = (bf16_t*)(ws);             // [0,24)   [8192,1536] (qh|ql|qh)
  bf16_t* kcat  = (bf16_t*)(ws + 24 * MB);   // [24,48)  [8192,1536] (kh|kh|kl)
  bf16_t* GA    = (bf16_t*)(ws + 48 * MB);   // [48,60)  Wk split (h|l|h)
  bf16_t* GB    = (bf16_t*)(ws + 60 * MB);   // [60,72)  Wq split (h|h|l)
  float*  Gpart = (float*)(ws + 72 * MB);    // [72,88)  16x[512,512]
  float*  Gt    = (float*)(ws + 88 * MB);    // [88,89)  SCALE*Wk.Wq^T
  bf16_t* Gtcat = (bf16_t*)(ws + 89 * MB);   // [89,91)  [512,1536]
  float*  tbuf  = (float*)(ws + 91 * MB);    // [91,107) [8192,512]
  bf16_t* tcat  = (bf16_t*)(ws + 107 * MB);  // [107,131) [8192,1536]
  float*  wqbk  = (float*)(ws + 131 * MB);
  float*  wkbq  = (float*)(ws + 131 * MB + 16 * 1024);
  float*  cdot  = (float*)(ws + 131 * MB + 32 * 1024);
  float*  rav   = (float*)(ws + 131 * MB + 64 * 1024);   // [8192]
  float*  rbv   = (float*)(ws + 131 * MB + 128 * 1024);  // [8192]
  float*  crcp  = (float*)(ws + 131 * MB + 192 * 1024);  // [8192]
  float*  part  = (float*)(ws + 131 * MB + 256 * 1024);  // 512 KB
  bf16_t* P     = (bf16_t*)(ws + 132 * MB);  // [132,164) 4x[2048,2048]
  // ---- phase B (v path, after P GEMM; reuses [0,76)) ----
  float*  WoTf   = (float*)(ws);             // [0,8)   Wo^T f32 [512,4096]
  bf16_t* WoS    = (bf16_t*)(ws + 8 * MB);   // [8,20)  Wo^T split (h|l|h)
  bf16_t* WvS    = (bf16_t*)(ws + 20 * MB);  // [20,32) Wv split (h|h|l)
  float*  WvoTp  = (float*)(ws + 32 * MB);   // [32,48) 16x[512,512]
  float*  WvoTf  = (float*)(ws + 48 * MB);   // [48,49) Wvo^T f32
  bf16_t* WvoTb  = (bf16_t*)(ws + 49 * MB);  // [49,50)
  float*  bvo    = (float*)(ws + 50 * MB);   // [512]
  bf16_t* vbf    = (bf16_t*)(ws + 51 * MB);  // [51,59)
  bf16_t* vo     = (bf16_t*)(ws + 59 * MB);  // [59,67)
  bf16_t* vosT   = (bf16_t*)(ws + 67 * MB);  // [67,75) [B][512,2048]

  // --- score path: scores = q.(SCALE*Wq.Wk^T).k^T + rank-1 bias terms ---
  split3<<<2048, 256, 0, stream>>>(q,  qcat, NROW * HID, 9, 0, 1, 0);
  split3<<<2048, 256, 0, stream>>>(k,  kcat, NROW * HID, 9, 0, 0, 1);
  split3<<<2048, 256, 0, stream>>>(Wk, GA, (long)HID * PROJ, 12, 0, 1, 0);
  split3<<<2048, 256, 0, stream>>>(Wq, GB, (long)HID * PROJ, 12, 0, 0, 1);

  gemm_bt<float, false><<<dim3(4, 4, 16), 256, 0, stream>>>(GA, GB, Gpart,
      nullptr, nullptr, nullptr, 1.0f, HID, HID, 768, 3L * PROJ, 3L * PROJ,
      768, 768, (long)HID * HID, 0);
  reduceG<<<(HID * HID + 255) / 256, 256, 0, stream>>>(Gpart, Gt, SCALE, HID * HID, 16);
  split3<<<1024, 256, 0, stream>>>(Gt, Gtcat, (long)HID * HID, 9, 0, 0, 1);

  gemm_bt<float, false><<<dim3(4, 64, 1), 256, 0, stream>>>(qcat, Gtcat, tbuf,
      nullptr, nullptr, nullptr, 1.0f, (int)NROW, HID, 1536, 1536, 1536, 0, 0, 0, 0);
  split3<<<2048, 256, 0, stream>>>(tbuf, tcat, NROW * HID, 9, 0, 1, 0);

  matvec<<<HID, 256, 0, stream>>>(Wq, bk, wqbk, PROJ);
  matvec<<<HID, 256, 0, stream>>>(Wk, bq, wkbq, PROJ);
  dotk<<<1, 256, 0, stream>>>(bq, bk, cdot, PROJ);
  rowdot<<<(int)NROW, 256, 0, stream>>>(q, wqbk, cdot, SCALE, rav, HID);
  rowdot<<<(int)NROW, 256, 0, stream>>>(k, wkbq, nullptr, SCALE, rbv, HID);

  // P = exp(t.k^T + ra + rb)
  gemm_bt<bf16_t, true><<<dim3(16, 16, BSZ), 256, 0, stream>>>(tcat, kcat, P,
      nullptr, rav, rbv, 1.0f, SEQ, SEQ, 1536, 1536, 1536,
      (long)SEQ * 1536, (long)SEQ * 1536, (long)SEQ * SEQ, SEQ);

  // column sums -> 1/csum
  colsum_part<<<dim3(SEQ / 256, 16, BSZ), 256, 0, stream>>>(P, part, SEQ, SEQ, SEQ / 16);
  colsum_final<<<dim3(SEQ / 256, BSZ), 256, 0, stream>>>(part, crcp, SEQ, 16);

  // --- v path: out = P.(vo/csum) + bo, vo = v.(Wv.Wo) + bv.Wo ---
  transpose_f32<<<dim3(HID / 32, PROJ / 32), 256, 0, stream>>>(Wo, WoTf, PROJ, HID);
  split3<<<2048, 256, 0, stream>>>(WoTf, WoS, (long)HID * PROJ, 12, 0, 1, 0);
  split3<<<2048, 256, 0, stream>>>(Wv,   WvS, (long)HID * PROJ, 12, 0, 0, 1);
  // WvoT[d,h] = sum_p Wo[p,d]*Wv[h,p]  (K=12288 split-16)
  gemm_bt<float, false><<<dim3(4, 4, 16), 256, 0, stream>>>(WoS, WvS, WvoTp,
      nullptr, nullptr, nullptr, 1.0f, HID, HID, 768, 3L * PROJ, 3L * PROJ,
      768, 768, (long)HID * HID, 0);
  reduceG<<<(HID * HID + 255) / 256, 256, 0, stream>>>(WvoTp, WvoTf, 1.0f, HID * HID, 16);
  cast_f32_bf16<<<256, 256, 0, stream>>>(WvoTf, WvoTb, (long)HID * HID);
  matvec<<<HID, 256, 0, stream>>>(WoTf, bv, bvo, PROJ);  // bvo = Wo^T.bv

  cast_f32_bf16<<<2048, 256, 0, stream>>>(v, vbf, NROW * HID);
  // vo = v.Wvo + bvo  (bf16 out)
  gemm_bt<bf16_t, false><<<dim3(HID / 128, NROW / 128, 1), 256, 0, stream>>>(
      vbf, WvoTb, vo, bvo, nullptr, nullptr, 1.0f, (int)NROW, HID, HID,
      HID, HID, 0, 0, 0, 0);
  // vosT[z][d,m] = vo[z][m,d] / csum[z][m]
  transpose_scale_bf16<<<dim3(HID / 64, SEQ / 64, BSZ), 256, 0, stream>>>(
      vo, crcp, vosT, SEQ, HID, (long)SEQ * HID, (long)HID * SEQ);

  // out = P.vosT^T + bo  (f32)
  gemm_bt<float, false><<<dim3(HID / 128, SEQ / 128, BSZ), 256, 0, stream>>>(
      P, vosT, out, bo, nullptr, nullptr, 1.0f, SEQ, HID, SEQ,
      SEQ, SEQ, (long)SEQ * SEQ, (long)HID * SEQ, (long)SEQ * HID, 0);
}